// Round 9
// baseline (1303.753 us; speedup 1.0000x reference)
//
#include <hip/hip_runtime.h>
#include <stdint.h>

#define H 512
#define B_SZ 1024
#define T_WARM 256
#define NSTEPS 64
#define TOTAL_T (T_WARM + NSTEPS)

#define RPB 16          // rows per team
#define HC 128          // cols per block
#define NTEAM 64        // B_SZ / RPB
#define NCG 4           // H / HC
#define NBLK 256        // NTEAM * NCG == CU count, 1 block/CU
#define NTHR 512        // 8 waves
#define HSTR 520        // padded LDS k-stride (ushorts)

typedef __attribute__((ext_vector_type(8))) short bf16x8;
typedef __attribute__((ext_vector_type(4))) float f32x4;

__device__ __forceinline__ ushort f2bf(float f) {
    uint32_t u = __builtin_bit_cast(uint32_t, f);
    u += 0x7FFFu + ((u >> 16) & 1u);
    return (ushort)(u >> 16);
}
__device__ __forceinline__ float bf2f(ushort h) {
    uint32_t u = ((uint32_t)h) << 16;
    return __builtin_bit_cast(float, u);
}

// Exchange format: hi-plane / lo-plane, u32 = bf16(col 2p) | bf16(col 2p+1)<<16,
// plane[row*256 + p]. Consumer staging needs ZERO unpack ALU (b64 loads -> ds_write_b64).
__global__ void prep_kernel(const float* __restrict__ x,
                            const float* __restrict__ W_hh,
                            const float* __restrict__ b_ih,
                            const float* __restrict__ b_hh,
                            ushort* __restrict__ Wh, ushort* __restrict__ Wl,
                            float* __restrict__ bias, float* __restrict__ xT,
                            uint32_t* __restrict__ Hhi0, uint32_t* __restrict__ Hlo0,
                            uint32_t* __restrict__ flags) {
    int i = blockIdx.x * NTHR + threadIdx.x;     // [0, 524288)
    if (i < B_SZ * 256) { Hhi0[i] = 0u; Hlo0[i] = 0u; }   // h(0) = 0
    if (i < 4096) flags[i] = 0u;
    if (i < H * H) {
        float w = W_hh[i];
        ushort hi = f2bf(w);
        float rem = w - bf2f(hi);
        Wh[i] = hi;
        Wl[i] = f2bf(rem);
    }
    if (i < B_SZ * T_WARM) {
        int b = i & (B_SZ - 1), t = i >> 10;
        xT[t * B_SZ + b] = x[b * T_WARM + t];
    }
    if (i < H) bias[i] = b_ih[i] + b_hh[i];
}

__global__ __launch_bounds__(NTHR, 1)
void rnn_kernel(const float* __restrict__ xT,
                const float* __restrict__ W_ih,
                const float* __restrict__ b_fc_p,
                const float* __restrict__ W_fc,
                const ushort* __restrict__ Wh_g,
                const ushort* __restrict__ Wl_g,
                const float* __restrict__ bias_g,
                uint32_t* __restrict__ Hhi0, uint32_t* __restrict__ Hhi1,
                uint32_t* __restrict__ Hlo0, uint32_t* __restrict__ Hlo1,
                uint32_t* __restrict__ flags,
                float* __restrict__ out) {
    __shared__ ushort h_hi[2][RPB * HSTR];   // ping-pong, 2 x 16640 B
    __shared__ ushort h_lo[2][RPB * HSTR];
    __shared__ uint32_t tr[RPB * HC];        // packed (hi<<16)|lo scratch, 8 KB
    __shared__ float w_fc_s[H];
    __shared__ float w_in_s[HC];
    __shared__ float bias_s[HC];
    __shared__ float sx[RPB];
    __shared__ float sy[RPB];

    const int tid = threadIdx.x;
    const int bid = blockIdx.x;
    const int team = bid & (NTEAM - 1);    // blocks {team,+64,+128,+192} share bid%8 (perf only)
    const int cg = bid >> 6;               // 0..3
    const int row0 = team * RPB;
    const int col0 = cg * HC;

    w_fc_s[tid & (H - 1)] = W_fc[tid & (H - 1)];
    if (tid < HC) { w_in_s[tid] = W_ih[col0 + tid]; bias_s[tid] = bias_g[col0 + tid]; }
    const float bfc = b_fc_p[0];

    const int lane = tid & 63;
    const int wv = tid >> 6;               // col-tile within block == k-slice id
    const int n = lane & 15, q = lane >> 4;

    // ---- weights register-resident: wave wv owns cols [col0+wv*16, +16), K=512 ----
    bf16x8 Bh[16], Bl[16];
    {
        const ushort* wh = Wh_g + (col0 + wv * 16 + n) * H + q * 8;
        const ushort* wl = Wl_g + (col0 + wv * 16 + n) * H + q * 8;
        #pragma unroll
        for (int kt = 0; kt < 16; ++kt) {
            Bh[kt] = *(const bf16x8*)(wh + kt * 32);
            Bl[kt] = *(const bf16x8*)(wl + kt * 32);
        }
    }

    uint32_t* myflag = flags + (team * NCG + cg) * 16;
    const uint32_t* pollflag = flags + (team * NCG + (wv >> 1)) * 16;
    const bool selfw = ((wv >> 1) == cg);

    // staging geometry: wave wv stages k-cols [wv*64,+64) = u32 pairs p in [wv*32,+32)
    const int sr = lane & 15;              // row handled by this lane
    const int sg = lane >> 4;              // 0..3: p-subgroup of 8 pairs

    for (int t = 0; t < TOTAL_T; ++t) {
        float xv = 0.f;
        if (t < T_WARM && tid < RPB) xv = xT[t * B_SZ + row0 + tid];

        ushort* hhb = h_hi[t & 1];
        ushort* hlb = h_lo[t & 1];

        if (t > 0 && selfw) {
            // self slice from LDS scratch (packed) -- unpack as r8
            #pragma unroll
            for (int it = 0; it < 8; ++it) {
                int idx = it * 64 + lane;
                int r = idx >> 5, cpair = idx & 31;
                int kloc = (wv & 1) * 64 + cpair * 2;
                uint32_t w0 = tr[r * HC + kloc];
                uint32_t w1 = tr[r * HC + kloc + 1];
                uint32_t hw = (w0 >> 16) | (w1 & 0xFFFF0000u);
                uint32_t lw = (w0 & 0xFFFFu) | (w1 << 16);
                int k = wv * 64 + cpair * 2;
                *(uint32_t*)(&hhb[r * HSTR + k]) = hw;
                *(uint32_t*)(&hlb[r * HSTR + k]) = lw;
            }
        } else {
            if (t > 0) {
                while (__hip_atomic_load(pollflag, __ATOMIC_RELAXED, __HIP_MEMORY_SCOPE_AGENT)
                       < (uint32_t)t)
                    __builtin_amdgcn_s_sleep(1);
            }
            const uint64_t* srch = (const uint64_t*)((t & 1) ? Hhi1 : Hhi0);
            const uint64_t* srcl = (const uint64_t*)((t & 1) ? Hlo1 : Hlo0);
            const int bu = (row0 + sr) * 128 + wv * 16 + sg * 4;   // u64 index
            uint64_t th[4], tl[4];
            #pragma unroll
            for (int j = 0; j < 4; ++j)
                th[j] = __hip_atomic_load(srch + bu + j, __ATOMIC_RELAXED, __HIP_MEMORY_SCOPE_AGENT);
            #pragma unroll
            for (int j = 0; j < 4; ++j)
                tl[j] = __hip_atomic_load(srcl + bu + j, __ATOMIC_RELAXED, __HIP_MEMORY_SCOPE_AGENT);
            // zero-ALU restage: b64 writes in final layout
            #pragma unroll
            for (int j = 0; j < 4; ++j) {
                int k = wv * 64 + sg * 16 + j * 4;
                *(uint64_t*)(&hhb[sr * HSTR + k]) = th[j];
                *(uint64_t*)(&hlb[sr * HSTR + k]) = tl[j];
            }
        }
        if (t < T_WARM && tid < RPB) sx[tid] = xv;
        __syncthreads();   // E: all slices staged; orders tr reads vs epilogue rewrite

        // ---- rollout: y = h . w_fc + b_fc (redundant per cg; cg0 writes out) ----
        if (t >= T_WARM) {
            if (tid < RPB * 16) {
                int r = tid >> 4, seg = tid & 15;
                const ushort* hh = &hhb[r * HSTR];
                const ushort* hl = &hlb[r * HSTR];
                float s = 0.f;
                #pragma unroll
                for (int kk = 0; kk < 32; ++kk) {
                    int k = seg + kk * 16;
                    s += (bf2f(hh[k]) + bf2f(hl[k])) * w_fc_s[k];
                }
                #pragma unroll
                for (int off = 8; off; off >>= 1) s += __shfl_down(s, off, 16);
                if (seg == 0) {
                    float y = s + bfc;
                    sy[r] = y;
                    if (cg == 0) out[(row0 + r) * NSTEPS + (t - T_WARM)] = y;
                }
            }
            __syncthreads();
        }

        // ---- MFMA: A(16x512) @ B(512x16), 16 kt x 3 hi/lo terms ----
        f32x4 acc0 = {0.f, 0.f, 0.f, 0.f}, acc1 = {0.f, 0.f, 0.f, 0.f};
        const ushort* ha = &hhb[n * HSTR] + q * 8;
        const ushort* la = &hlb[n * HSTR] + q * 8;
        #pragma unroll
        for (int kt = 0; kt < 16; kt += 2) {
            {
                bf16x8 ah = *(const bf16x8*)(ha + kt * 32);
                bf16x8 al = *(const bf16x8*)(la + kt * 32);
                acc0 = __builtin_amdgcn_mfma_f32_16x16x32_bf16(ah, Bh[kt], acc0, 0, 0, 0);
                acc0 = __builtin_amdgcn_mfma_f32_16x16x32_bf16(al, Bh[kt], acc0, 0, 0, 0);
                acc0 = __builtin_amdgcn_mfma_f32_16x16x32_bf16(ah, Bl[kt], acc0, 0, 0, 0);
            }
            {
                bf16x8 ah = *(const bf16x8*)(ha + (kt + 1) * 32);
                bf16x8 al = *(const bf16x8*)(la + (kt + 1) * 32);
                acc1 = __builtin_amdgcn_mfma_f32_16x16x32_bf16(ah, Bh[kt + 1], acc1, 0, 0, 0);
                acc1 = __builtin_amdgcn_mfma_f32_16x16x32_bf16(al, Bh[kt + 1], acc1, 0, 0, 0);
                acc1 = __builtin_amdgcn_mfma_f32_16x16x32_bf16(ah, Bl[kt + 1], acc1, 0, 0, 0);
            }
        }

        // ---- epilogue: relu(acc + s*w_in + bias) -> packed tr (LDS only) ----
        const int jl = wv * 16 + n;
        const float wi = w_in_s[jl], bj = bias_s[jl];
        #pragma unroll
        for (int i = 0; i < 4; ++i) {
            int m = q * 4 + i;                     // C/D: row = quad*4+reg, col = lane&15
            float sv = (t < T_WARM) ? sx[m] : sy[m];
            float v = acc0[i] + acc1[i] + sv * wi + bj;
            v = fmaxf(v, 0.f);
            ushort hi = f2bf(v);
            float rem = v - bf2f(hi);
            tr[m * HC + jl] = ((uint32_t)hi << 16) | (uint32_t)f2bf(rem);
        }
        __syncthreads();   // I1: tr complete (LDS-only dependency)

        // ---- store phase: coalesced u64 stores to hi/lo planes ----
        {
            int r = tid >> 5, seg = tid & 31;      // row r, 4-col group seg
            const uint32_t* tp = &tr[r * HC + seg * 4];
            uint32_t w0 = tp[0], w1 = tp[1], w2 = tp[2], w3 = tp[3];
            uint64_t hu = (uint64_t)((w0 >> 16) | (w1 & 0xFFFF0000u))
                        | ((uint64_t)((w2 >> 16) | (w3 & 0xFFFF0000u)) << 32);
            uint64_t lu = (uint64_t)((w0 & 0xFFFFu) | (w1 << 16))
                        | ((uint64_t)((w2 & 0xFFFFu) | (w3 << 16)) << 32);
            uint64_t* dsth = (uint64_t*)((t & 1) ? Hhi0 : Hhi1);
            uint64_t* dstl = (uint64_t*)((t & 1) ? Hlo0 : Hlo1);
            int du = (row0 + r) * 128 + cg * 32 + seg;
            __hip_atomic_store(dsth + du, hu, __ATOMIC_RELAXED, __HIP_MEMORY_SCOPE_AGENT);
            __hip_atomic_store(dstl + du, lu, __ATOMIC_RELAXED, __HIP_MEMORY_SCOPE_AGENT);
        }
        __syncthreads();   // I2: drains all waves' vmem (vmcnt0) before flag publish
        if (tid == 0)
            __hip_atomic_store(myflag, (uint32_t)(t + 1), __ATOMIC_RELAXED, __HIP_MEMORY_SCOPE_AGENT);
    }
}

extern "C" void kernel_launch(void* const* d_in, const int* in_sizes, int n_in,
                              void* d_out, int out_size, void* d_ws, size_t ws_size,
                              hipStream_t stream) {
    const float* x    = (const float*)d_in[0];
    const float* W_ih = (const float*)d_in[1];
    const float* W_hh = (const float*)d_in[2];
    const float* b_ih = (const float*)d_in[3];
    const float* b_hh = (const float*)d_in[4];
    const float* W_fc = (const float*)d_in[5];
    const float* b_fc = (const float*)d_in[6];
    float* out = (float*)d_out;

    // ws carve (bytes): Wh 512K | Wl 512K | bias 4K | xT 1M | Hhi0 1M | Hhi1 1M | Hlo0 1M | Hlo1 1M | flags 16K
    uint8_t* w = (uint8_t*)d_ws;
    ushort*   Wh    = (ushort*)(w);
    ushort*   Wl    = (ushort*)(w + 524288);
    float*    bias  = (float*)(w + 1048576);
    float*    xT    = (float*)(w + 1052672);
    uint32_t* Hhi0  = (uint32_t*)(w + 2101248);
    uint32_t* Hhi1  = (uint32_t*)(w + 3149824);
    uint32_t* Hlo0  = (uint32_t*)(w + 4198400);
    uint32_t* Hlo1  = (uint32_t*)(w + 5246976);
    uint32_t* flags = (uint32_t*)(w + 6295552);

    prep_kernel<<<1024, NTHR, 0, stream>>>(x, W_hh, b_ih, b_hh, Wh, Wl, bias, xT, Hhi0, Hlo0, flags);
    rnn_kernel<<<NBLK, NTHR, 0, stream>>>(xT, W_ih, b_fc, W_fc, Wh, Wl, bias,
                                          Hhi0, Hhi1, Hlo0, Hlo1, flags, out);
}

// Round 10
// 1171.552 us; speedup vs baseline: 1.1128x; 1.1128x over previous
//
#include <hip/hip_runtime.h>
#include <stdint.h>

#define H 512
#define B_SZ 1024
#define T_WARM 256
#define NSTEPS 64
#define TOTAL_T (T_WARM + NSTEPS)

#define RPB 16          // rows per team
#define HC 64           // cols per block
#define NTEAM 64        // B_SZ / RPB
#define NCG 8           // H / HC
#define NBLK 512        // NTEAM * NCG == 2 blocks/CU (latency hiding)
#define NTHR 256        // 4 waves
#define HSTR 520        // padded LDS k-stride (ushorts)

typedef __attribute__((ext_vector_type(8))) short bf16x8;
typedef __attribute__((ext_vector_type(4))) float f32x4;

__device__ __forceinline__ ushort f2bf(float f) {
    uint32_t u = __builtin_bit_cast(uint32_t, f);
    u += 0x7FFFu + ((u >> 16) & 1u);
    return (ushort)(u >> 16);
}
__device__ __forceinline__ float bf2f(ushort h) {
    uint32_t u = ((uint32_t)h) << 16;
    return __builtin_bit_cast(float, u);
}

__global__ void prep_kernel(const float* __restrict__ x,
                            const float* __restrict__ W_hh,
                            const float* __restrict__ b_ih,
                            const float* __restrict__ b_hh,
                            ushort* __restrict__ Wh, ushort* __restrict__ Wl,
                            float* __restrict__ bias, float* __restrict__ xT,
                            uint32_t* __restrict__ Hb0, uint32_t* __restrict__ flags) {
    int i = blockIdx.x * 512 + threadIdx.x;      // [0, 524288)
    Hb0[i] = 0u;                                  // h(0) = 0 (packed)
    if (i < 4096) flags[i] = 0u;
    if (i < H * H) {
        float w = W_hh[i];
        ushort hi = f2bf(w);
        float rem = w - bf2f(hi);
        Wh[i] = hi;
        Wl[i] = f2bf(rem);
    }
    if (i < B_SZ * T_WARM) {
        int b = i & (B_SZ - 1), t = i >> 10;
        xT[t * B_SZ + b] = x[b * T_WARM + t];
    }
    if (i < H) bias[i] = b_ih[i] + b_hh[i];
}

__global__ __launch_bounds__(NTHR, 2)
void rnn_kernel(const float* __restrict__ xT,
                const float* __restrict__ W_ih,
                const float* __restrict__ b_fc_p,
                const float* __restrict__ W_fc,
                const ushort* __restrict__ Wh_g,
                const ushort* __restrict__ Wl_g,
                const float* __restrict__ bias_g,
                uint32_t* __restrict__ Hb0, uint32_t* __restrict__ Hb1,
                uint32_t* __restrict__ flags,
                float* __restrict__ out) {
    __shared__ ushort h_hi[2][RPB * HSTR];   // ping-pong, 2 x 16640 B
    __shared__ ushort h_lo[2][RPB * HSTR];
    __shared__ float w_fc_s[H];
    __shared__ float w_in_s[HC];
    __shared__ float bias_s[HC];
    __shared__ float sx[RPB];
    __shared__ float sy[RPB];

    const int tid = threadIdx.x;
    const int bid = blockIdx.x;
    const int team = bid & (NTEAM - 1);    // team members share bid%8 (XCD residue, perf only)
    const int cg = bid >> 6;               // 0..7
    const int row0 = team * RPB;
    const int col0 = cg * HC;

    for (int i = tid; i < H; i += NTHR) w_fc_s[i] = W_fc[i];
    if (tid < HC) { w_in_s[tid] = W_ih[col0 + tid]; bias_s[tid] = bias_g[col0 + tid]; }
    const float bfc = b_fc_p[0];

    const int lane = tid & 63;
    const int wv = tid >> 6;               // 0..3: col-tile AND k-slice id
    const int n = lane & 15, q = lane >> 4;

    // ---- weights register-resident: wave wv owns cols [col0+wv*16, +16), K=512 ----
    bf16x8 Bh[16], Bl[16];
    {
        const ushort* wh = Wh_g + (col0 + wv * 16 + n) * H + q * 8;
        const ushort* wl = Wl_g + (col0 + wv * 16 + n) * H + q * 8;
        #pragma unroll
        for (int kt = 0; kt < 16; ++kt) {
            Bh[kt] = *(const bf16x8*)(wh + kt * 32);
            Bl[kt] = *(const bf16x8*)(wl + kt * 32);
        }
    }

    // flags: u32 flags[team*16 + cg] (64 B per team). Producer publishes own; consumer
    // wave wv polls producers 2wv, 2wv+1 as one u64 (self-flag treated as ready).
    uint32_t* myflag = flags + team * 16 + cg;
    const uint64_t* pollp = (const uint64_t*)(flags + team * 16 + 2 * wv);
    const bool s0 = (2 * wv == cg), s1 = (2 * wv + 1 == cg);

    for (int t = 0; t < TOTAL_T; ++t) {
        float xv = 0.f;
        if (t < T_WARM && tid < RPB) xv = xT[t * B_SZ + row0 + tid];

        // ---- wait for this wave's 2 producers ----
        if (t > 0) {
            const uint32_t tt = (uint32_t)t;
            for (;;) {
                uint64_t f = __hip_atomic_load(pollp, __ATOMIC_RELAXED, __HIP_MEMORY_SCOPE_AGENT);
                uint32_t f0 = (uint32_t)f, f1 = (uint32_t)(f >> 32);
                if ((s0 || f0 >= tt) && (s1 || f1 >= tt)) break;
                __builtin_amdgcn_s_sleep(1);
            }
        }

        // ---- stage own k-slice [wv*128, +128) x 16 rows: 16 coalesced 512B row-loads ----
        uint64_t tmp[16];
        {
            const uint32_t* hb = (t & 1) ? Hb1 : Hb0;
            const uint64_t* src = (const uint64_t*)hb;   // row stride 256 u64
            #pragma unroll
            for (int r = 0; r < 16; ++r)
                tmp[r] = __hip_atomic_load(src + (row0 + r) * 256 + wv * 64 + lane,
                                           __ATOMIC_RELAXED, __HIP_MEMORY_SCOPE_AGENT);
        }
        // unpack to ping-pong buf (t&1); no pre-barrier needed (other buf was read last step)
        ushort* hhb = h_hi[t & 1];
        ushort* hlb = h_lo[t & 1];
        #pragma unroll
        for (int r = 0; r < 16; ++r) {
            uint64_t u = tmp[r];
            uint32_t w0 = (uint32_t)u, w1 = (uint32_t)(u >> 32);
            uint32_t hw = (w0 >> 16) | (w1 & 0xFFFF0000u);
            uint32_t lw = (w0 & 0xFFFFu) | (w1 << 16);
            int k = wv * 128 + lane * 2;
            *(uint32_t*)(&hhb[r * HSTR + k]) = hw;
            *(uint32_t*)(&hlb[r * HSTR + k]) = lw;
        }
        if (t < T_WARM && tid < RPB) sx[tid] = xv;
        __syncthreads();   // E: all 4 slices staged

        // ---- rollout: y = h . w_fc + b_fc (redundant per cg; cg0 writes out) ----
        if (t >= T_WARM) {
            {
                int r = tid >> 4, seg = tid & 15;      // all 256 threads
                const ushort* hh = &hhb[r * HSTR];
                const ushort* hl = &hlb[r * HSTR];
                float s = 0.f;
                #pragma unroll
                for (int kk = 0; kk < 32; ++kk) {
                    int k = seg + kk * 16;
                    s += (bf2f(hh[k]) + bf2f(hl[k])) * w_fc_s[k];
                }
                #pragma unroll
                for (int off = 8; off; off >>= 1) s += __shfl_down(s, off, 16);
                if (seg == 0) {
                    float y = s + bfc;
                    sy[r] = y;
                    if (cg == 0) out[(row0 + r) * NSTEPS + (t - T_WARM)] = y;
                }
            }
            __syncthreads();
        }

        // ---- MFMA: A(16x512) @ B(512x16), 16 kt x 3 hi/lo terms ----
        f32x4 acc0 = {0.f, 0.f, 0.f, 0.f}, acc1 = {0.f, 0.f, 0.f, 0.f};
        const ushort* ha = &hhb[n * HSTR] + q * 8;
        const ushort* la = &hlb[n * HSTR] + q * 8;
        #pragma unroll
        for (int kt = 0; kt < 16; kt += 2) {
            {
                bf16x8 ah = *(const bf16x8*)(ha + kt * 32);
                bf16x8 al = *(const bf16x8*)(la + kt * 32);
                acc0 = __builtin_amdgcn_mfma_f32_16x16x32_bf16(ah, Bh[kt], acc0, 0, 0, 0);
                acc0 = __builtin_amdgcn_mfma_f32_16x16x32_bf16(al, Bh[kt], acc0, 0, 0, 0);
                acc0 = __builtin_amdgcn_mfma_f32_16x16x32_bf16(ah, Bl[kt], acc0, 0, 0, 0);
            }
            {
                bf16x8 ah = *(const bf16x8*)(ha + (kt + 1) * 32);
                bf16x8 al = *(const bf16x8*)(la + (kt + 1) * 32);
                acc1 = __builtin_amdgcn_mfma_f32_16x16x32_bf16(ah, Bh[kt + 1], acc1, 0, 0, 0);
                acc1 = __builtin_amdgcn_mfma_f32_16x16x32_bf16(al, Bh[kt + 1], acc1, 0, 0, 0);
                acc1 = __builtin_amdgcn_mfma_f32_16x16x32_bf16(ah, Bl[kt + 1], acc1, 0, 0, 0);
            }
        }

        // ---- epilogue: relu(acc + s*w_in + bias) -> packed u32, store immediately ----
        const int jl = wv * 16 + n;
        const float wi = w_in_s[jl], bj = bias_s[jl];
        uint32_t* dst = ((t & 1) ? Hb0 : Hb1) + col0 + jl;
        #pragma unroll
        for (int i = 0; i < 4; ++i) {
            int m = q * 4 + i;                     // C/D: row = quad*4+reg, col = lane&15
            float sv = (t < T_WARM) ? sx[m] : sy[m];
            float v = acc0[i] + acc1[i] + sv * wi + bj;
            v = fmaxf(v, 0.f);
            ushort hi = f2bf(v);
            float rem = v - bf2f(hi);
            uint32_t u = ((uint32_t)hi << 16) | (uint32_t)f2bf(rem);
            __hip_atomic_store(dst + (row0 + m) * H, u, __ATOMIC_RELAXED, __HIP_MEMORY_SCOPE_AGENT);
        }
        __syncthreads();   // I: drains all waves' vmem (vmcnt0) before flag publish
        if (tid == 0)
            __hip_atomic_store(myflag, (uint32_t)(t + 1), __ATOMIC_RELAXED, __HIP_MEMORY_SCOPE_AGENT);
    }
}

extern "C" void kernel_launch(void* const* d_in, const int* in_sizes, int n_in,
                              void* d_out, int out_size, void* d_ws, size_t ws_size,
                              hipStream_t stream) {
    const float* x    = (const float*)d_in[0];
    const float* W_ih = (const float*)d_in[1];
    const float* W_hh = (const float*)d_in[2];
    const float* b_ih = (const float*)d_in[3];
    const float* b_hh = (const float*)d_in[4];
    const float* W_fc = (const float*)d_in[5];
    const float* b_fc = (const float*)d_in[6];
    float* out = (float*)d_out;

    // ws carve (bytes): Wh 512K | Wl 512K | bias 4K | xT 1M | Hb0 2M | Hb1 2M | flags 16K
    uint8_t* w = (uint8_t*)d_ws;
    ushort*   Wh    = (ushort*)(w);
    ushort*   Wl    = (ushort*)(w + 524288);
    float*    bias  = (float*)(w + 1048576);
    float*    xT    = (float*)(w + 1052672);
    uint32_t* Hb0   = (uint32_t*)(w + 2101248);
    uint32_t* Hb1   = (uint32_t*)(w + 4198400);
    uint32_t* flags = (uint32_t*)(w + 6295552);

    prep_kernel<<<1024, 512, 0, stream>>>(x, W_hh, b_ih, b_hh, Wh, Wl, bias, xT, Hb0, flags);
    rnn_kernel<<<NBLK, NTHR, 0, stream>>>(xT, W_ih, b_fc, W_fc, Wh, Wl, bias, Hb0, Hb1, flags, out);
}